// Round 1
// baseline (294.411 us; speedup 1.0000x reference)
//
#include <hip/hip_runtime.h>
#include <math.h>

#define NROWS 200000
#define DCOLS 512
#define NC 3
#define AGRID 512
#define CGRID 2048

__device__ __forceinline__ float elu1(float x) {
    // jax.nn.elu alpha=1: x>0 ? x : expm1(x). __expf-1 is accurate enough
    // (abs err ~1e-8 near 0) for the 8e-3 output threshold.
    return x > 0.0f ? x : __expf(x) - 1.0f;
}

__global__ void zero_sums(float* sums) {
    int t = blockIdx.x * blockDim.x + threadIdx.x;
    if (t < NC * DCOLS) sums[t] = 0.0f;
}

// Per-class column sums of `base` rows (base = feature when train==0,
// elu(weight*seq) when train==1). Thread t owns columns 2t, 2t+1 — the
// 3-class partials live entirely in 6 registers; no LDS, no intra-block
// races. Tail: 6 global atomicAdds per thread into the 1536-float sums.
__global__ __launch_bounds__(256) void segsum_kernel(
        const float* __restrict__ feature, const float* __restrict__ seq,
        const float* __restrict__ weight, const int* __restrict__ labels,
        const int* __restrict__ train, float* __restrict__ sums) {
    const int t = threadIdx.x;
    const int col = 2 * t;
    float ax0 = 0.f, ay0 = 0.f, ax1 = 0.f, ay1 = 0.f, ax2 = 0.f, ay2 = 0.f;
    const int tr = train[0];
    float wx = 0.f, wy = 0.f;
    if (tr) { float2 w = *(const float2*)(weight + col); wx = w.x; wy = w.y; }
    const float* srcbase = tr ? seq : feature;
    for (int row = blockIdx.x; row < NROWS; row += AGRID) {
        const int lab = labels[row];                       // block-uniform
        float2 v = *(const float2*)(srcbase + (size_t)row * DCOLS + col);
        float vx = v.x, vy = v.y;
        if (tr) { vx = elu1(wx * vx); vy = elu1(wy * vy); }
        if (lab == 0)      { ax0 += vx; ay0 += vy; }
        else if (lab == 1) { ax1 += vx; ay1 += vy; }
        else               { ax2 += vx; ay2 += vy; }
    }
    atomicAdd(&sums[0 * DCOLS + col],     ax0);
    atomicAdd(&sums[0 * DCOLS + col + 1], ay0);
    atomicAdd(&sums[1 * DCOLS + col],     ax1);
    atomicAdd(&sums[1 * DCOLS + col + 1], ay1);
    atomicAdd(&sums[2 * DCOLS + col],     ax2);
    atomicAdd(&sums[2 * DCOLS + col + 1], ay2);
}

// ave = sums / (N/2); an[c] = ||ave[c]||. Single block.
__global__ __launch_bounds__(256) void ave_norm_kernel(
        const float* __restrict__ sums, float* __restrict__ ave,
        float* __restrict__ an) {
    __shared__ float red[4];
    const int t = threadIdx.x, lane = t & 63, wv = t >> 6;
    const float inv = 1.0f / (float)(NROWS / 2);
    for (int c = 0; c < NC; ++c) {
        float p = 0.0f;
        for (int j = t; j < DCOLS; j += 256) {
            float v = sums[c * DCOLS + j] * inv;
            ave[c * DCOLS + j] = v;
            p += v * v;
        }
        for (int o = 32; o; o >>= 1) p += __shfl_xor(p, o);
        if (lane == 0) red[wv] = p;
        __syncthreads();
        if (t == 0) an[c] = sqrtf(red[0] + red[1] + red[2] + red[3]);
        __syncthreads();
    }
}

__device__ __forceinline__ void proc4(float4 s, float4 w,
                                      float4 a0, float4 a1, float4 a2,
                                      float& rn2, float& d0, float& d1, float& d2) {
    float r;
    r = elu1(w.x * s.x); rn2 = fmaf(r, r, rn2); d0 = fmaf(r, a0.x, d0); d1 = fmaf(r, a1.x, d1); d2 = fmaf(r, a2.x, d2);
    r = elu1(w.y * s.y); rn2 = fmaf(r, r, rn2); d0 = fmaf(r, a0.y, d0); d1 = fmaf(r, a1.y, d1); d2 = fmaf(r, a2.y, d2);
    r = elu1(w.z * s.z); rn2 = fmaf(r, r, rn2); d0 = fmaf(r, a0.z, d0); d1 = fmaf(r, a1.z, d1); d2 = fmaf(r, a2.z, d2);
    r = elu1(w.w * s.w); rn2 = fmaf(r, r, rn2); d0 = fmaf(r, a0.w, d0); d1 = fmaf(r, a1.w, d1); d2 = fmaf(r, a2.w, d2);
}

// One wave per row. Lane l owns cols [4l,4l+4) and [256+4l,256+4l+4):
// weight + 3 ave rows held in registers (no LDS, no re-reads).
// Butterfly-reduce {rn2,d0,d1,d2}; lanes 0..2 write the softmax row.
__global__ __launch_bounds__(256) void cosine_softmax_kernel(
        const float* __restrict__ seq, const float* __restrict__ weight,
        const float* __restrict__ ave, const float* __restrict__ an3,
        float* __restrict__ out) {
    const int lane = threadIdx.x & 63;
    const int wv = threadIdx.x >> 6;
    const int b0 = 4 * lane, b1 = 256 + 4 * lane;
    const float4 w0 = *(const float4*)(weight + b0);
    const float4 w1 = *(const float4*)(weight + b1);
    const float4 a00 = *(const float4*)(ave + 0 * DCOLS + b0);
    const float4 a01 = *(const float4*)(ave + 0 * DCOLS + b1);
    const float4 a10 = *(const float4*)(ave + 1 * DCOLS + b0);
    const float4 a11 = *(const float4*)(ave + 1 * DCOLS + b1);
    const float4 a20 = *(const float4*)(ave + 2 * DCOLS + b0);
    const float4 a21 = *(const float4*)(ave + 2 * DCOLS + b1);
    const float an0 = an3[0], an1 = an3[1], an2 = an3[2];
    for (int row = blockIdx.x * 4 + wv; row < NROWS; row += gridDim.x * 4) {
        const float* srow = seq + (size_t)row * DCOLS;
        float4 s0 = *(const float4*)(srow + b0);
        float4 s1 = *(const float4*)(srow + b1);
        float rn2 = 0.f, d0 = 0.f, d1 = 0.f, d2 = 0.f;
        proc4(s0, w0, a00, a10, a20, rn2, d0, d1, d2);
        proc4(s1, w1, a01, a11, a21, rn2, d0, d1, d2);
        #pragma unroll
        for (int o = 32; o; o >>= 1) {
            rn2 += __shfl_xor(rn2, o);
            d0  += __shfl_xor(d0, o);
            d1  += __shfl_xor(d1, o);
            d2  += __shfl_xor(d2, o);
        }
        if (lane < 3) {
            const float rn = sqrtf(rn2);
            float s0v = d0 / fmaxf(rn * an0, 1e-8f);
            float s1v = d1 / fmaxf(rn * an1, 1e-8f);
            float s2v = d2 / fmaxf(rn * an2, 1e-8f);
            float m = fmaxf(s0v, fmaxf(s1v, s2v));
            float e0 = __expf(s0v - m), e1 = __expf(s1v - m), e2 = __expf(s2v - m);
            float inv = 1.0f / (e0 + e1 + e2);
            float p = (lane == 0) ? e0 : (lane == 1 ? e1 : e2);
            out[(size_t)row * 3 + lane] = p * inv;
        }
    }
}

extern "C" void kernel_launch(void* const* d_in, const int* in_sizes, int n_in,
                              void* d_out, int out_size, void* d_ws, size_t ws_size,
                              hipStream_t stream) {
    const float* seq     = (const float*)d_in[0];
    const float* feature = (const float*)d_in[1];
    const int*   labels  = (const int*)d_in[2];
    const float* weight  = (const float*)d_in[3];
    const int*   train   = (const int*)d_in[4];
    float* out = (float*)d_out;

    float* sums = (float*)d_ws;           // 1536 floats
    float* ave  = sums + NC * DCOLS;      // 1536 floats
    float* an   = ave + NC * DCOLS;       // 3 floats   (~12.3 KB total ws)

    zero_sums<<<6, 256, 0, stream>>>(sums);
    segsum_kernel<<<AGRID, 256, 0, stream>>>(feature, seq, weight, labels, train, sums);
    ave_norm_kernel<<<1, 256, 0, stream>>>(sums, ave, an);
    cosine_softmax_kernel<<<CGRID, 256, 0, stream>>>(seq, weight, ave, an, out);
}

// Round 2
// 235.054 us; speedup vs baseline: 1.2525x; 1.2525x over previous
//
#include <hip/hip_runtime.h>
#include <math.h>

#define NROWS 200000
#define DCOLS 512
#define NC 3
#define SGRID 1024
#define NFULL 196608   // 12 full steps * SGRID*16 rows
#define TAILB 212      // (NROWS-NFULL)/16 blocks cover the tail exactly
#define CGRID 2048

__device__ __forceinline__ float elu1(float x) {
    return x > 0.0f ? x : __expf(x) - 1.0f;
}

__global__ void zero_sums(float* sums) {
    int t = blockIdx.x * blockDim.x + threadIdx.x;
    if (t < NC * DCOLS) sums[t] = 0.0f;
}

// 8 independent rows per thread per step (static-index v[8] -> registers),
// float4 per lane, half-block (128 lanes) per row => coalesced 2KB row loads.
#define BODY8(base)                                                          \
    {                                                                        \
        const float* p = src + (size_t)(base) * DCOLS + c4;                  \
        int lb[8]; float4 v[8];                                              \
        _Pragma("unroll") for (int j = 0; j < 8; ++j)                        \
            lb[j] = labels[(base) + j];                                      \
        _Pragma("unroll") for (int j = 0; j < 8; ++j)                        \
            v[j] = *(const float4*)(p + (size_t)j * DCOLS);                  \
        _Pragma("unroll") for (int j = 0; j < 8; ++j) {                      \
            float4 x = v[j];                                                 \
            if (tr) { x.x = elu1(w.x * x.x); x.y = elu1(w.y * x.y);          \
                      x.z = elu1(w.z * x.z); x.w = elu1(w.w * x.w); }        \
            if (lb[j] == 0)      { a0.x += x.x; a0.y += x.y;                 \
                                   a0.z += x.z; a0.w += x.w; }               \
            else if (lb[j] == 1) { a1.x += x.x; a1.y += x.y;                 \
                                   a1.z += x.z; a1.w += x.w; }               \
            else                 { a2.x += x.x; a2.y += x.y;                 \
                                   a2.z += x.z; a2.w += x.w; }               \
        }                                                                    \
    }

__global__ __launch_bounds__(256) void segsum_kernel(
        const float* __restrict__ feature, const float* __restrict__ seq,
        const float* __restrict__ weight, const int* __restrict__ labels,
        const int* __restrict__ train, float* __restrict__ sums) {
    const int t = threadIdx.x;
    const int c4 = (t & 127) << 2;   // column base (4 floats)
    const int h  = t >> 7;           // half-block id: row parity within step
    const int tr = train[0];
    float4 w = make_float4(0.f, 0.f, 0.f, 0.f);
    if (tr) w = *(const float4*)(weight + c4);
    const float* __restrict__ src = tr ? seq : feature;
    float4 a0 = {0,0,0,0}, a1 = {0,0,0,0}, a2 = {0,0,0,0};

    for (int base = blockIdx.x * 16 + h * 8; base < NFULL; base += SGRID * 16)
        BODY8(base);
    if (blockIdx.x < TAILB)
        BODY8(NFULL + blockIdx.x * 16 + h * 8);

    // halves-reduce in LDS, then one atomicAdd per (class,col) per block
    __shared__ float red[NC][128][4];
    if (h == 1) {
        const int c = t & 127;
        *(float4*)red[0][c] = a0;
        *(float4*)red[1][c] = a1;
        *(float4*)red[2][c] = a2;
    }
    __syncthreads();
    if (h == 0) {
        const int c = t;
        a0.x += red[0][c][0]; a0.y += red[0][c][1]; a0.z += red[0][c][2]; a0.w += red[0][c][3];
        a1.x += red[1][c][0]; a1.y += red[1][c][1]; a1.z += red[1][c][2]; a1.w += red[1][c][3];
        a2.x += red[2][c][0]; a2.y += red[2][c][1]; a2.z += red[2][c][2]; a2.w += red[2][c][3];
        atomicAdd(&sums[0 * DCOLS + c4 + 0], a0.x);
        atomicAdd(&sums[0 * DCOLS + c4 + 1], a0.y);
        atomicAdd(&sums[0 * DCOLS + c4 + 2], a0.z);
        atomicAdd(&sums[0 * DCOLS + c4 + 3], a0.w);
        atomicAdd(&sums[1 * DCOLS + c4 + 0], a1.x);
        atomicAdd(&sums[1 * DCOLS + c4 + 1], a1.y);
        atomicAdd(&sums[1 * DCOLS + c4 + 2], a1.z);
        atomicAdd(&sums[1 * DCOLS + c4 + 3], a1.w);
        atomicAdd(&sums[2 * DCOLS + c4 + 0], a2.x);
        atomicAdd(&sums[2 * DCOLS + c4 + 1], a2.y);
        atomicAdd(&sums[2 * DCOLS + c4 + 2], a2.z);
        atomicAdd(&sums[2 * DCOLS + c4 + 3], a2.w);
    }
}

// ave = sums / (N/2); an[c] = ||ave[c]||. Single block.
__global__ __launch_bounds__(256) void ave_norm_kernel(
        const float* __restrict__ sums, float* __restrict__ ave,
        float* __restrict__ an) {
    __shared__ float red[4];
    const int t = threadIdx.x, lane = t & 63, wv = t >> 6;
    const float inv = 1.0f / (float)(NROWS / 2);
    for (int c = 0; c < NC; ++c) {
        float p = 0.0f;
        for (int j = t; j < DCOLS; j += 256) {
            float v = sums[c * DCOLS + j] * inv;
            ave[c * DCOLS + j] = v;
            p += v * v;
        }
        for (int o = 32; o; o >>= 1) p += __shfl_xor(p, o);
        if (lane == 0) red[wv] = p;
        __syncthreads();
        if (t == 0) an[c] = sqrtf(red[0] + red[1] + red[2] + red[3]);
        __syncthreads();
    }
}

__device__ __forceinline__ void proc4(float4 s, float4 w,
                                      float4 a0, float4 a1, float4 a2,
                                      float& rn2, float& d0, float& d1, float& d2) {
    float r;
    r = elu1(w.x * s.x); rn2 = fmaf(r, r, rn2); d0 = fmaf(r, a0.x, d0); d1 = fmaf(r, a1.x, d1); d2 = fmaf(r, a2.x, d2);
    r = elu1(w.y * s.y); rn2 = fmaf(r, r, rn2); d0 = fmaf(r, a0.y, d0); d1 = fmaf(r, a1.y, d1); d2 = fmaf(r, a2.y, d2);
    r = elu1(w.z * s.z); rn2 = fmaf(r, r, rn2); d0 = fmaf(r, a0.z, d0); d1 = fmaf(r, a1.z, d1); d2 = fmaf(r, a2.z, d2);
    r = elu1(w.w * s.w); rn2 = fmaf(r, r, rn2); d0 = fmaf(r, a0.w, d0); d1 = fmaf(r, a1.w, d1); d2 = fmaf(r, a2.w, d2);
}

// One wave per row. Lane l owns cols [4l,4l+4) and [256+4l,256+4l+4):
// weight + 3 ave rows held in registers (no LDS, no re-reads).
__global__ __launch_bounds__(256) void cosine_softmax_kernel(
        const float* __restrict__ seq, const float* __restrict__ weight,
        const float* __restrict__ ave, const float* __restrict__ an3,
        float* __restrict__ out) {
    const int lane = threadIdx.x & 63;
    const int wv = threadIdx.x >> 6;
    const int b0 = 4 * lane, b1 = 256 + 4 * lane;
    const float4 w0 = *(const float4*)(weight + b0);
    const float4 w1 = *(const float4*)(weight + b1);
    const float4 a00 = *(const float4*)(ave + 0 * DCOLS + b0);
    const float4 a01 = *(const float4*)(ave + 0 * DCOLS + b1);
    const float4 a10 = *(const float4*)(ave + 1 * DCOLS + b0);
    const float4 a11 = *(const float4*)(ave + 1 * DCOLS + b1);
    const float4 a20 = *(const float4*)(ave + 2 * DCOLS + b0);
    const float4 a21 = *(const float4*)(ave + 2 * DCOLS + b1);
    const float an0 = an3[0], an1 = an3[1], an2 = an3[2];
    for (int row = blockIdx.x * 4 + wv; row < NROWS; row += CGRID * 4) {
        const float* srow = seq + (size_t)row * DCOLS;
        float4 s0 = *(const float4*)(srow + b0);
        float4 s1 = *(const float4*)(srow + b1);
        float rn2 = 0.f, d0 = 0.f, d1 = 0.f, d2 = 0.f;
        proc4(s0, w0, a00, a10, a20, rn2, d0, d1, d2);
        proc4(s1, w1, a01, a11, a21, rn2, d0, d1, d2);
        #pragma unroll
        for (int o = 32; o; o >>= 1) {
            rn2 += __shfl_xor(rn2, o);
            d0  += __shfl_xor(d0, o);
            d1  += __shfl_xor(d1, o);
            d2  += __shfl_xor(d2, o);
        }
        if (lane < 3) {
            const float rn = sqrtf(rn2);
            float s0v = d0 / fmaxf(rn * an0, 1e-8f);
            float s1v = d1 / fmaxf(rn * an1, 1e-8f);
            float s2v = d2 / fmaxf(rn * an2, 1e-8f);
            float m = fmaxf(s0v, fmaxf(s1v, s2v));
            float e0 = __expf(s0v - m), e1 = __expf(s1v - m), e2 = __expf(s2v - m);
            float inv = 1.0f / (e0 + e1 + e2);
            float p = (lane == 0) ? e0 : (lane == 1 ? e1 : e2);
            out[(size_t)row * 3 + lane] = p * inv;
        }
    }
}

extern "C" void kernel_launch(void* const* d_in, const int* in_sizes, int n_in,
                              void* d_out, int out_size, void* d_ws, size_t ws_size,
                              hipStream_t stream) {
    const float* seq     = (const float*)d_in[0];
    const float* feature = (const float*)d_in[1];
    const int*   labels  = (const int*)d_in[2];
    const float* weight  = (const float*)d_in[3];
    const int*   train   = (const int*)d_in[4];
    float* out = (float*)d_out;

    float* sums = (float*)d_ws;           // 1536 floats
    float* ave  = sums + NC * DCOLS;      // 1536 floats
    float* an   = ave + NC * DCOLS;       // 3 floats

    zero_sums<<<6, 256, 0, stream>>>(sums);
    segsum_kernel<<<SGRID, 256, 0, stream>>>(feature, seq, weight, labels, train, sums);
    ave_norm_kernel<<<1, 256, 0, stream>>>(sums, ave, an);
    cosine_softmax_kernel<<<CGRID, 256, 0, stream>>>(seq, weight, ave, an, out);
}